// Round 9
// baseline (146.507 us; speedup 1.0000x reference)
//
#include <hip/hip_runtime.h>
#include <stdint.h>

// ---------------------------------------------------------------------------
// LIL loss v9. b=1024, N=32768, d=128.  TWO launches:
//  convert: f32->bf16 (K swizzled 64-col/16KB tiles, Q plain) + qf hist
//           partials + zero `done`.
//  gemm:    grid (N/512, b/128)=512 blocks, 512 thr (8 waves). A in regs;
//           B 64-col subtiles double-buffered (2x16KB) via global_load_lds
//           from pre-swizzled ws. qf hoisted to 4 packed-byte VGPRs.
//           Per-element: class-encoded max, sum exp2 via bias-fma, sum dot
//           over positives. Partial slice per block; LAST block (done
//           counter) folds all slices + hist + fallback + finalize -> out.
// ws: [0) done u32 | [256) histP u32[64][32] (8K) | [32K) part float4[64*b]
//     (1M) | [+1M) KbB bf16 swizzled (8M) | then Qb bf16[b*128]
// ---------------------------------------------------------------------------

typedef short bf16x8 __attribute__((ext_vector_type(8)));
typedef unsigned short ushort8v __attribute__((ext_vector_type(8)));
typedef float f32x4 __attribute__((ext_vector_type(4)));

#define INV_T 14.285714285714286f  // 1/0.07
#define K2E 20.609929155698604f    // log2(e)/0.07

__device__ __forceinline__ unsigned short f2bf(float x) {
    unsigned u = __float_as_uint(x);
    return (unsigned short)((u + 0x7FFFu + ((u >> 16) & 1u)) >> 16);
}
__device__ __forceinline__ ushort8v cvt8(const float4* s4) {
    float4 a = s4[0], b = s4[1];
    ushort8v v;
    v[0] = f2bf(a.x); v[1] = f2bf(a.y); v[2] = f2bf(a.z); v[3] = f2bf(a.w);
    v[4] = f2bf(b.x); v[5] = f2bf(b.y); v[6] = f2bf(b.z); v[7] = f2bf(b.w);
    return v;
}
__device__ __forceinline__ void gload_lds16(const void* g, void* l) {
    __builtin_amdgcn_global_load_lds(
        (const __attribute__((address_space(1))) unsigned int*)g,
        (__attribute__((address_space(3))) unsigned int*)l, 16, 0, 0);
}

__global__ void convert_kernel(const float* __restrict__ Q,
                               const float* __restrict__ Kv,
                               const int* __restrict__ qf,
                               unsigned short* __restrict__ Qb,
                               char* __restrict__ KbB,
                               unsigned* __restrict__ histP,
                               unsigned* __restrict__ done, int N, int b) {
    __shared__ unsigned lh[32];
    const int t = threadIdx.x;
    const int blk = blockIdx.x;
    if (blk == 0 && t == 0) *done = 0u;
    if (blk < 64) {
        if (t < 32) lh[t] = 0u;
        __syncthreads();
        int j0 = blk * 512;
        atomicAdd(&lh[qf[j0 + t] + 1], 1u);
        atomicAdd(&lh[qf[j0 + 256 + t] + 1], 1u);
        __syncthreads();
        if (t < 32) histP[blk * 32 + t] = lh[t];
    }
    int i = blk * 256 + t;
    int nk = N * 16;
    if (i < nk) {
        int row = i >> 4, kc = i & 15;
        ushort8v v = cvt8(reinterpret_cast<const float4*>(
            Kv + (size_t)row * 128 + kc * 8));
        int tb = row >> 6, rr = row & 63;
        int off = tb * 16384 + ((rr * 256 + kc * 16) ^ ((rr & 7) << 4));
        *reinterpret_cast<ushort8v*>(KbB + off) = v;
    } else if (i < nk + b * 16) {
        int j = i - nk;
        int row = j >> 4, kc = j & 15;
        ushort8v v = cvt8(reinterpret_cast<const float4*>(
            Q + (size_t)row * 128 + kc * 8));
        *reinterpret_cast<ushort8v*>((char*)Qb + row * 256 + kc * 16) = v;
    }
}

__global__ __launch_bounds__(512, 2) void gemm_kernel(
    const unsigned short* __restrict__ Qb, const char* __restrict__ KbB,
    const float* __restrict__ Qf, const float* __restrict__ Kvf,
    const int* __restrict__ flags, const int* __restrict__ qf,
    const int* __restrict__ n_iter_p, float4* __restrict__ part,
    const unsigned* __restrict__ histP, unsigned* __restrict__ done,
    float* __restrict__ out, int N, int b)
{
    __shared__ __align__(16) char sB[2][16384];
    __shared__ unsigned sh[32];
    __shared__ int sNum;
    __shared__ unsigned sLastFlag;
    __shared__ unsigned sU[8];
    __shared__ float sF[8];
    __shared__ unsigned sTotN;

    const int tid = threadIdx.x;
    const int lane = tid & 63, g = lane >> 4, q = lane & 15;
    const int wave = tid >> 6, wr = wave >> 1, wc = wave & 1;
    const int bx = blockIdx.x;
    const int r0 = blockIdx.y * 128;

    // ---- A fragments (32 VGPR), flags packed (2 VGPR), qf packed (4 VGPR)
    bf16x8 af[2][4];
#pragma unroll
    for (int mi = 0; mi < 2; ++mi) {
        int row = r0 + 32 * wr + 16 * mi + q;
#pragma unroll
        for (int ks = 0; ks < 4; ++ks)
            af[mi][ks] = *reinterpret_cast<const bf16x8*>(
                Qb + (size_t)row * 128 + ks * 32 + g * 8);
    }
    unsigned flpack[2];
#pragma unroll
    for (int mi = 0; mi < 2; ++mi) {
        unsigned p = 0;
#pragma unroll
        for (int reg = 0; reg < 4; ++reg) {
            int f = flags[r0 + 32 * wr + 16 * mi + 4 * g + reg];
            unsigned byte = (f < 0) ? 255u : (unsigned)(f + 1);
            p |= byte << (8 * reg);
        }
        flpack[mi] = p;
    }
    unsigned qpack[4];
#pragma unroll
    for (int w = 0; w < 4; ++w) {
        unsigned p = 0;
#pragma unroll
        for (int bvi = 0; bvi < 4; ++bvi) {
            int v = w * 4 + bvi;  // v = t*2 + ni
            int tt = v >> 1, ni = v & 1;
            int col = bx * 512 + tt * 64 + 32 * wc + 16 * ni + q;
            p |= ((unsigned)(qf[col] + 1) & 255u) << (8 * bvi);
        }
        qpack[w] = p;
    }

    float bestp[8], se[8], sl[8];
#pragma unroll
    for (int r = 0; r < 8; ++r) { bestp[r] = -3.0e38f; se[r] = 0.f; sl[r] = 0.f; }

#define STAGE(buf, gt)                                                 \
    {                                                                  \
        const char* s_ = KbB + (size_t)(gt) * 16384 + tid * 16;        \
        char* d_ = &sB[buf][tid * 16];                                 \
        gload_lds16(s_, d_);                                           \
        gload_lds16(s_ + 8192, d_ + 8192);                             \
    }

    STAGE(0, bx * 8);

#pragma unroll
    for (int t = 0; t < 8; ++t) {
        __syncthreads();
        if (t < 7) STAGE((t + 1) & 1, bx * 8 + t + 1);
        const char* bb = sB[t & 1];

        f32x4 acc[2][2];
#pragma unroll
        for (int mi = 0; mi < 2; ++mi)
#pragma unroll
            for (int ni = 0; ni < 2; ++ni) acc[mi][ni] = (f32x4){0, 0, 0, 0};

#pragma unroll
        for (int ks = 0; ks < 4; ++ks) {
            bf16x8 bf[2];
#pragma unroll
            for (int ni = 0; ni < 2; ++ni) {
                int rr = 32 * wc + 16 * ni + q;
                bf[ni] = *reinterpret_cast<const bf16x8*>(
                    bb + ((rr * 256 + ks * 64 + g * 16) ^ ((rr & 7) << 4)));
            }
#pragma unroll
            for (int mi = 0; mi < 2; ++mi)
#pragma unroll
                for (int ni = 0; ni < 2; ++ni)
                    acc[mi][ni] = __builtin_amdgcn_mfma_f32_16x16x32_bf16(
                        af[mi][ks], bf[ni], acc[mi][ni], 0, 0, 0);
        }

        unsigned qv1[2] = {(qpack[t >> 1] >> (((2 * t) & 3) * 8)) & 255u,
                           (qpack[t >> 1] >> (((2 * t + 1) & 3) * 8)) & 255u};
        // bias -1024: exp2 underflows to exact 0 for qf==-1 columns;
        // fma(dot,K2E,+0) rounds identically to dot*K2E on the live path.
        float bias[2] = {(qv1[0] == 0u) ? -1024.f : 0.f,
                         (qv1[1] == 0u) ? -1024.f : 0.f};
#pragma unroll
        for (int mi = 0; mi < 2; ++mi)
#pragma unroll
            for (int reg = 0; reg < 4; ++reg) {
                int rr8 = mi * 4 + reg;
                unsigned fc = (flpack[mi] >> (8 * reg)) & 255u;
                float bp = bestp[rr8], s = se[rr8], l = sl[rr8];
#pragma unroll
                for (int ni = 0; ni < 2; ++ni) {
                    float dot = acc[mi][ni][reg];
                    s += exp2f(__builtin_fmaf(dot, K2E, bias[ni]));
                    l += (qv1[ni] == fc) ? dot : 0.f;
                    float dp = __uint_as_float(
                        (__float_as_uint(dot) & ~31u) | qv1[ni]);
                    bp = fmaxf(bp, dp);
                }
                bestp[rr8] = bp; se[rr8] = s; sl[rr8] = l;
            }
    }

    // ---- fold q 16->1 per row-half, cross-fold wc via LDS, write slice
    float4* scr = (float4*)sB;  // first 4 KB of sB
#pragma unroll
    for (int rr8 = 0; rr8 < 8; ++rr8) {
        float bp = bestp[rr8], s = se[rr8], l = sl[rr8];
#pragma unroll
        for (int off = 1; off < 16; off <<= 1) {
            float ob = __shfl_xor(bp, off);
            float os = __shfl_xor(s, off);
            float ol = __shfl_xor(l, off);
            bp = fmaxf(bp, ob);
            s += os;
            l += ol;
        }
        if (q == 0) {
            int rl = 32 * wr + 16 * (rr8 >> 2) + 4 * g + (rr8 & 3);
            scr[wc * 128 + rl] = make_float4(bp, s, l, 0.f);
        }
    }
    __syncthreads();
    if (tid < 128) {
        float4 a = scr[tid], c = scr[128 + tid];
        part[(size_t)bx * b + r0 + tid] =
            make_float4(fmaxf(a.x, c.x), a.y + c.y, a.z + c.z, 0.f);
    }

    // ---- last-block finalize
    __threadfence();
    if (tid == 0) {
        unsigned old = atomicAdd(done, 1u);
        sLastFlag = (old == gridDim.x * gridDim.y - 1) ? 1u : 0u;
        sNum = 0;
    }
    __syncthreads();
    if (!sLastFlag) return;
    __threadfence();  // acquire: all slices visible

    char* base = &sB[0][0];
    float* sBp = (float*)base;                     // [1024] 4 KB
    float* sSl = (float*)(base + 4096);            // [1024] 4 KB
    float* sQrow = (float*)(base + 8192);          // [128]  512 B
    int* sList = (int*)(base + 8704);              // [1024] 4 KB
    unsigned* sWrong = (unsigned*)(base + 12800);  // [1024] 4 KB

    // hist fold
    if (tid < 32) {
        unsigned s = 0;
#pragma unroll
        for (int i = 0; i < 64; ++i) s += histP[i * 32 + tid];
        sh[tid] = s;
    }
    // fold 64 slices for rows rA=tid, rB=tid+512
    const int rA = tid, rB = tid + 512;
    float bpA = -3.0e38f, seA = 0.f, slA = 0.f;
    float bpB = -3.0e38f, seB = 0.f, slB = 0.f;
    for (int cs = 0; cs < 64; ++cs) {
        float4 pa = part[(size_t)cs * b + rA];
        float4 pb = part[(size_t)cs * b + rB];
        bpA = fmaxf(bpA, pa.x); seA += pa.y; slA += pa.z;
        bpB = fmaxf(bpB, pb.x); seB += pb.y; slB += pb.z;
    }
    __syncthreads();  // sB reads done (scr); safe to overwrite
    sBp[rA] = bpA; sSl[rA] = slA;
    sBp[rB] = bpB; sSl[rB] = slB;

    const int fA = flags[rA], fB = flags[rB];
    __syncthreads();  // sh, sBp, sSl ready
    unsigned cntA = (fA >= 0) ? sh[fA + 1] : 0u;
    unsigned cntB = (fB >= 0) ? sh[fB + 1] : 0u;
    float ubA = (float)cntA / ((float)(N - (int)cntA) + 1e-6f);
    float ubB = (float)cntB / ((float)(N - (int)cntB) + 1e-6f);
    const int nit = *n_iter_p;
    if (nit >= 0 && ubA > 10.0f) sList[atomicAdd(&sNum, 1)] = rA;
    if (nit >= 0 && ubB > 10.0f) sList[atomicAdd(&sNum, 1)] = rB;
    __syncthreads();
    const int nt = sNum;  // normally 0
    for (int i = 0; i < nt; ++i) {
        int rr = sList[i];
        if (tid == 0) sWrong[i] = 0u;
        if (tid < 128) sQrow[tid] = Qf[(size_t)rr * 128 + tid];
        __syncthreads();
        int f = flags[rr];
        unsigned c = (f >= 0) ? sh[f + 1] : 0u;
        float m = sBp[rr] * INV_T;
        float mean = (INV_T * sSl[rr] - (float)c * m) / (float)N;
        int wp = 0;
        for (int j = tid; j < N; j += 512) {
            float dot = 0.f;
            const float* kr = Kvf + (size_t)j * 128;
            for (int k = 0; k < 128; ++k) dot += sQrow[k] * kr[k];
            bool mask = (f == qf[j]) && (f != -1);
            float lfp = mask ? (dot * INV_T - m) : 0.f;
            if (lfp < mean) wp++;
        }
        atomicAdd(&sWrong[i], (unsigned)wp);
        __syncthreads();
    }

    // finalize both rows
    float sumlfpX[2], rowsumX[2];
    unsigned effX[2];
    int rX[2] = {rA, rB};
    int fX[2] = {fA, fB};
    unsigned cX[2] = {cntA, cntB};
    float bpX[2] = {bpA, bpB}, seX[2] = {seA, seB}, slX[2] = {slA, slB};
    float ubX[2] = {ubA, ubB};
#pragma unroll
    for (int s2 = 0; s2 < 2; ++s2) {
        int f = fX[s2];
        bool row_m1 = (f == -1);
        float mdot = bpX[s2];
        float m = mdot * INV_T;
        int qmax1 = (int)(__float_as_uint(mdot) & 31u);
        float rowsum;
        if (row_m1) {
            rowsum = 0.f;
        } else {
            float adj = seX[s2] - ((qmax1 == 0) ? 0.f : exp2f(mdot * K2E));
            rowsum = fmaxf(exp2f(-mdot * K2E) * adj, 0.f);
        }
        float sum_lfp = INV_T * slX[s2] - (float)cX[s2] * m;
        bool ispos = (!row_m1) && (qmax1 - 1 == f);
        unsigned nnz = cX[s2] - (ispos ? 1u : 0u);
        bool revise = false;
        if (nit >= 0 && ubX[s2] > 10.0f) {
            unsigned wr2 = 0;
            for (int i = 0; i < nt; ++i)
                if (sList[i] == rX[s2]) wr2 = sWrong[i];
            float wf = (float)wr2, pf = (float)(N - (int)wr2);
            revise = (wf / (pf + 1e-6f)) > 10.0f;
        }
        out[1 + rX[s2]] = (float)(revise ? 0 : f);
        sumlfpX[s2] = revise ? 0.f : sum_lfp;
        effX[s2] = revise ? 0u : nnz;
        rowsumX[s2] = rowsum;
    }

    // total_nnz reduction (512 thr = 8 waves)
    unsigned nn = effX[0] + effX[1];
#pragma unroll
    for (int off = 1; off < 64; off <<= 1) nn += __shfl_xor(nn, off);
    if (lane == 0) sU[wave] = nn;
    __syncthreads();
    if (tid == 0) {
        unsigned tot = 0;
#pragma unroll
        for (int i = 0; i < 8; ++i) tot += sU[i];
        sTotN = tot;
    }
    __syncthreads();
    unsigned total_nnz = sTotN;

    float contrib = 0.f;
#pragma unroll
    for (int s2 = 0; s2 < 2; ++s2) {
        float row_lp = sumlfpX[s2] - (float)N * logf(rowsumX[s2] + 1e-12f);
        contrib += (total_nnz > 0u && rowsumX[s2] > 0.f && row_lp < 0.f)
                       ? row_lp / (float)total_nnz
                       : 0.f;
    }
#pragma unroll
    for (int off = 1; off < 64; off <<= 1) contrib += __shfl_xor(contrib, off);
    if (lane == 0) sF[wave] = contrib;
    __syncthreads();
    if (tid == 0) {
        float tot = 0.f;
#pragma unroll
        for (int i = 0; i < 8; ++i) tot += sF[i];
        out[0] = -(tot / (float)b);  // TEMP/BASE_TEMP == 1
    }
}

extern "C" void kernel_launch(void* const* d_in, const int* in_sizes, int n_in,
                              void* d_out, int out_size, void* d_ws,
                              size_t ws_size, hipStream_t stream)
{
    const float* Q = (const float*)d_in[0];
    const float* Kall = (const float*)d_in[1];
    const int* flags = (const int*)d_in[2];
    const int* qfall = (const int*)d_in[3];
    const int* n_iter = (const int*)d_in[4];
    float* out = (float*)d_out;

    const int b = in_sizes[2];      // 1024
    const int total = in_sizes[3];  // 33792
    const int N = total - b;        // 32768
    const float* Kv = Kall + (size_t)b * 128;
    const int* qf = qfall + b;

    char* wsb = (char*)d_ws;
    unsigned* done = (unsigned*)wsb;
    unsigned* histP = (unsigned*)(wsb + 256);
    float4* part = (float4*)(wsb + 32768);
    char* KbB = wsb + 32768 + (size_t)64 * b * 16;  // +1 MB
    unsigned short* Qb = (unsigned short*)(KbB + (size_t)N * 256);

    int nconv = (N + b) * 16;
    convert_kernel<<<(nconv + 255) / 256, 256, 0, stream>>>(
        Q, Kv, qf, Qb, KbB, histP, done, N, b);

    dim3 grid(N / 512, b / 128);
    gemm_kernel<<<grid, 512, 0, stream>>>(Qb, KbB, Q, Kv, flags, qf, n_iter,
                                          part, histP, done, out, N, b);
}

// Round 10
// 82.356 us; speedup vs baseline: 1.7789x; 1.7789x over previous
//
#include <hip/hip_runtime.h>
#include <stdint.h>

// ---------------------------------------------------------------------------
// LIL loss v10 = v8 (proven 44.3us, absmax 0) + qpack hoist from v9.
// 4 launches:
//  convert: f32->bf16 (K swizzled 64-col/16KB tiles, Q plain) + qf hist
//           partials + zero wrongA.
//  gemm:    grid (N/512, b/128); 512 thr (8 waves). A in regs; B 64-col
//           subtiles double-buffered (2x16KB) via global_load_lds from
//           pre-swizzled ws. qf hoisted into 4 packed-byte VGPRs (t-loop
//           unrolled so indexing is static). Per-element: class-encoded
//           max, sum exp2 via bias-fma, sum dot over positives. One
//           partial slice per block.
//  reduce:  fold 64 slices/row + hist; exact wrong_cnt fallback scan for
//           rows that could revise (uniform early-exit normally).
//  final:   per-row finalize + 2 shuffle-reductions -> loss + flags out.
// NOTE: no __threadfence anywhere — device-scope fences on 8-XCD CDNA4
// force full dirty-L2 writebacks (124MB observed in v9); launches are the
// cheap fence.
// ws: [0K) bestA f32[b] | [4K) flagsA | [8K) sumlA | [12K) sumexpA
//     [16K) cntA | [20K) wrongA | [24K) histP u32[64][32]
//     [32K) part float4[64*b] (1 MB) | [+1M) KbB bf16 swizzled (8 MB)
//     [+9M) Qb bf16[b*128]
// ---------------------------------------------------------------------------

typedef short bf16x8 __attribute__((ext_vector_type(8)));
typedef unsigned short ushort8v __attribute__((ext_vector_type(8)));
typedef float f32x4 __attribute__((ext_vector_type(4)));

#define INV_T 14.285714285714286f  // 1/0.07
#define K2E 20.609929155698604f    // log2(e)/0.07

__device__ __forceinline__ unsigned short f2bf(float x) {
    unsigned u = __float_as_uint(x);
    return (unsigned short)((u + 0x7FFFu + ((u >> 16) & 1u)) >> 16);
}
__device__ __forceinline__ ushort8v cvt8(const float4* s4) {
    float4 a = s4[0], b = s4[1];
    ushort8v v;
    v[0] = f2bf(a.x); v[1] = f2bf(a.y); v[2] = f2bf(a.z); v[3] = f2bf(a.w);
    v[4] = f2bf(b.x); v[5] = f2bf(b.y); v[6] = f2bf(b.z); v[7] = f2bf(b.w);
    return v;
}
__device__ __forceinline__ void gload_lds16(const void* g, void* l) {
    __builtin_amdgcn_global_load_lds(
        (const __attribute__((address_space(1))) unsigned int*)g,
        (__attribute__((address_space(3))) unsigned int*)l, 16, 0, 0);
}

__global__ void convert_kernel(const float* __restrict__ Q,
                               const float* __restrict__ Kv,
                               const int* __restrict__ qf,
                               unsigned short* __restrict__ Qb,
                               char* __restrict__ KbB,
                               unsigned* __restrict__ histP,
                               unsigned* __restrict__ wrongA, int N, int b) {
    __shared__ unsigned lh[32];
    const int t = threadIdx.x;
    const int blk = blockIdx.x;
    if (blk < 64) {
        if (t < 32) lh[t] = 0u;
        __syncthreads();
        int j0 = blk * 512;
        atomicAdd(&lh[qf[j0 + t] + 1], 1u);
        atomicAdd(&lh[qf[j0 + 256 + t] + 1], 1u);
        __syncthreads();
        if (t < 32) histP[blk * 32 + t] = lh[t];
    }
    int i = blk * 256 + t;
    if (i < b) wrongA[i] = 0u;
    int nk = N * 16;
    if (i < nk) {
        int row = i >> 4, kc = i & 15;
        ushort8v v = cvt8(reinterpret_cast<const float4*>(
            Kv + (size_t)row * 128 + kc * 8));
        int tb = row >> 6, rr = row & 63;
        int off = tb * 16384 + ((rr * 256 + kc * 16) ^ ((rr & 7) << 4));
        *reinterpret_cast<ushort8v*>(KbB + off) = v;
    } else if (i < nk + b * 16) {
        int j = i - nk;
        int row = j >> 4, kc = j & 15;
        ushort8v v = cvt8(reinterpret_cast<const float4*>(
            Q + (size_t)row * 128 + kc * 8));
        *reinterpret_cast<ushort8v*>((char*)Qb + row * 256 + kc * 16) = v;
    }
}

__global__ __launch_bounds__(512, 2) void gemm_kernel(
    const unsigned short* __restrict__ Qb, const char* __restrict__ KbB,
    const int* __restrict__ flags, const int* __restrict__ qf,
    float4* __restrict__ part, int b)
{
    __shared__ __align__(16) char sB[2][16384];
    const int tid = threadIdx.x;
    const int lane = tid & 63, g = lane >> 4, q = lane & 15;
    const int wave = tid >> 6, wr = wave >> 1, wc = wave & 1;
    const int bx = blockIdx.x;
    const int r0 = blockIdx.y * 128;

    bf16x8 af[2][4];
#pragma unroll
    for (int mi = 0; mi < 2; ++mi) {
        int row = r0 + 32 * wr + 16 * mi + q;
#pragma unroll
        for (int ks = 0; ks < 4; ++ks)
            af[mi][ks] = *reinterpret_cast<const bf16x8*>(
                Qb + (size_t)row * 128 + ks * 32 + g * 8);
    }
    unsigned flpack[2];
#pragma unroll
    for (int mi = 0; mi < 2; ++mi) {
        unsigned p = 0;
#pragma unroll
        for (int reg = 0; reg < 4; ++reg) {
            int f = flags[r0 + 32 * wr + 16 * mi + 4 * g + reg];
            unsigned byte = (f < 0) ? 255u : (unsigned)(f + 1);
            p |= byte << (8 * reg);
        }
        flpack[mi] = p;
    }
    // qf hoisted: 16 values (8 iters x 2 ni) packed as bytes in 4 VGPRs
    unsigned qpack[4];
#pragma unroll
    for (int w = 0; w < 4; ++w) {
        unsigned p = 0;
#pragma unroll
        for (int bvi = 0; bvi < 4; ++bvi) {
            int v = w * 4 + bvi;  // v = t*2 + ni
            int tt = v >> 1, ni = v & 1;
            int col = bx * 512 + tt * 64 + 32 * wc + 16 * ni + q;
            p |= ((unsigned)(qf[col] + 1) & 255u) << (8 * bvi);
        }
        qpack[w] = p;
    }

    float bestp[8], se[8], sl[8];
#pragma unroll
    for (int r = 0; r < 8; ++r) { bestp[r] = -3.0e38f; se[r] = 0.f; sl[r] = 0.f; }

#define STAGE(buf, gt)                                                 \
    {                                                                  \
        const char* s_ = KbB + (size_t)(gt) * 16384 + tid * 16;        \
        char* d_ = &sB[buf][tid * 16];                                 \
        gload_lds16(s_, d_);                                           \
        gload_lds16(s_ + 8192, d_ + 8192);                             \
    }

    STAGE(0, bx * 8);

#pragma unroll
    for (int t = 0; t < 8; ++t) {
        __syncthreads();
        if (t < 7) STAGE((t + 1) & 1, bx * 8 + t + 1);
        const char* bb = sB[t & 1];

        f32x4 acc[2][2];
#pragma unroll
        for (int mi = 0; mi < 2; ++mi)
#pragma unroll
            for (int ni = 0; ni < 2; ++ni) acc[mi][ni] = (f32x4){0, 0, 0, 0};

#pragma unroll
        for (int ks = 0; ks < 4; ++ks) {
            bf16x8 bf[2];
#pragma unroll
            for (int ni = 0; ni < 2; ++ni) {
                int rr = 32 * wc + 16 * ni + q;
                bf[ni] = *reinterpret_cast<const bf16x8*>(
                    bb + ((rr * 256 + ks * 64 + g * 16) ^ ((rr & 7) << 4)));
            }
#pragma unroll
            for (int mi = 0; mi < 2; ++mi)
#pragma unroll
                for (int ni = 0; ni < 2; ++ni)
                    acc[mi][ni] = __builtin_amdgcn_mfma_f32_16x16x32_bf16(
                        af[mi][ks], bf[ni], acc[mi][ni], 0, 0, 0);
        }

        // static extraction (t-loop unrolled): qv1[ni] = qf[col(t,ni)] + 1
        unsigned qv1[2] = {(qpack[t >> 1] >> (((2 * t) & 3) * 8)) & 255u,
                           (qpack[t >> 1] >> (((2 * t + 1) & 3) * 8)) & 255u};
        // bias -1024: exp2 underflows to exact 0 for qf==-1 columns;
        // fma(dot,K2E,+0) rounds identically to dot*K2E on the live path.
        float bias[2] = {(qv1[0] == 0u) ? -1024.f : 0.f,
                         (qv1[1] == 0u) ? -1024.f : 0.f};
#pragma unroll
        for (int mi = 0; mi < 2; ++mi)
#pragma unroll
            for (int reg = 0; reg < 4; ++reg) {
                int rr8 = mi * 4 + reg;
                unsigned fc = (flpack[mi] >> (8 * reg)) & 255u;
                float bp = bestp[rr8], s = se[rr8], l = sl[rr8];
#pragma unroll
                for (int ni = 0; ni < 2; ++ni) {
                    float dot = acc[mi][ni][reg];
                    s += exp2f(__builtin_fmaf(dot, K2E, bias[ni]));
                    l += (qv1[ni] == fc) ? dot : 0.f;
                    float dp = __uint_as_float(
                        (__float_as_uint(dot) & ~31u) | qv1[ni]);
                    bp = fmaxf(bp, dp);
                }
                bestp[rr8] = bp; se[rr8] = s; sl[rr8] = l;
            }
    }

    float4* scr = (float4*)sB;  // 256 float4, overlays sB[0]
#pragma unroll
    for (int rr8 = 0; rr8 < 8; ++rr8) {
        float bp = bestp[rr8], s = se[rr8], l = sl[rr8];
#pragma unroll
        for (int off = 1; off < 16; off <<= 1) {
            float ob = __shfl_xor(bp, off);
            float os = __shfl_xor(s, off);
            float ol = __shfl_xor(l, off);
            bp = fmaxf(bp, ob);
            s += os;
            l += ol;
        }
        if (q == 0) {
            int rl = 32 * wr + 16 * (rr8 >> 2) + 4 * g + (rr8 & 3);
            scr[wc * 128 + rl] = make_float4(bp, s, l, 0.f);
        }
    }
    __syncthreads();
    if (tid < 128) {
        float4 a = scr[tid], c = scr[128 + tid];
        part[(size_t)bx * b + r0 + tid] =
            make_float4(fmaxf(a.x, c.x), a.y + c.y, a.z + c.z, 0.f);
    }
}

// 16 blocks x 64 rows: fold slices + hist; then (rarely) exact wrong_cnt
// scan for any row whose revise upper-bound cnt/(N-cnt) could exceed 10.
__global__ __launch_bounds__(256) void reduce_kernel(
    const float4* __restrict__ part, const int* __restrict__ flags,
    const unsigned* __restrict__ histP, const float* __restrict__ Q,
    const float* __restrict__ Kv, const int* __restrict__ qf,
    float* __restrict__ bestA, int* __restrict__ flagsA,
    float* __restrict__ sumlA, float* __restrict__ sumexpA,
    unsigned* __restrict__ cntA, unsigned* __restrict__ wrongA, int N, int b)
{
    __shared__ float4 red[4][64];
    __shared__ unsigned sh[32];
    __shared__ float sB64[64], sL64[64];
    __shared__ unsigned sC64[64];
    __shared__ int sList[64];
    __shared__ int sNum;
    __shared__ unsigned sWp;
    __shared__ float sQrow[128];

    const int t = threadIdx.x;
    if (t == 0) sNum = 0;
    if (t < 32) {
        unsigned s = 0;
#pragma unroll
        for (int i = 0; i < 64; ++i) s += histP[i * 32 + t];
        sh[t] = s;
    }
    const int rl = t & 63;
    const int r = blockIdx.x * 64 + rl;
    const int pg = t >> 6;
    float bp = -3.0e38f, s = 0.f, l = 0.f;
    for (int cs = pg; cs < 64; cs += 4) {
        float4 p = part[(size_t)cs * b + r];
        bp = fmaxf(bp, p.x);
        s += p.y;
        l += p.z;
    }
    red[pg][rl] = make_float4(bp, s, l, 0.f);
    __syncthreads();
    if (t < 64) {
        const int rr = blockIdx.x * 64 + t;
        bp = -3.0e38f; s = 0.f; l = 0.f;
#pragma unroll
        for (int i = 0; i < 4; ++i) {
            float4 p = red[i][t];
            bp = fmaxf(bp, p.x);
            s += p.y;
            l += p.z;
        }
        bestA[rr] = bp;
        flagsA[rr] = (int)(__float_as_uint(bp) & 31u);  // qf@argmax + 1
        sumexpA[rr] = s;
        sumlA[rr] = l;
        int f = flags[rr];
        unsigned c = (f >= 0) ? sh[f + 1] : 0u;
        cntA[rr] = c;
        sB64[t] = bp; sL64[t] = l; sC64[t] = c;
        float ub = (float)c / ((float)(N - (int)c) + 1e-6f);
        if (ub > 10.0f) {
            int slot = atomicAdd(&sNum, 1);
            sList[slot] = t;
        }
    }
    __syncthreads();
    const int nt = sNum;  // uniform; normally 0
    for (int i = 0; i < nt; ++i) {
        int rloc = sList[i];
        int rr = blockIdx.x * 64 + rloc;
        if (t == 0) sWp = 0u;
        if (t < 128) sQrow[t] = Q[(size_t)rr * 128 + t];
        __syncthreads();
        float m = sB64[rloc] * INV_T;
        unsigned c = sC64[rloc];
        float mean = (INV_T * sL64[rloc] - (float)c * m) / (float)N;
        int f = flags[rr];
        int wp = 0;
        for (int j = t; j < N; j += 256) {
            float dot = 0.f;
            const float* kr = Kv + (size_t)j * 128;
            for (int k = 0; k < 128; ++k) dot += sQrow[k] * kr[k];
            bool mask = (f == qf[j]) && (f != -1);
            float lfp = mask ? (dot * INV_T - m) : 0.f;
            if (lfp < mean) wp++;
        }
        atomicAdd(&sWp, (unsigned)wp);
        __syncthreads();
        if (t == 0) wrongA[rr] = sWp;
        __syncthreads();
    }
}

__global__ __launch_bounds__(1024) void final_kernel(
    const int* __restrict__ flags, const int* __restrict__ n_iter_p,
    const float* __restrict__ bestA, const int* __restrict__ flagsA,
    const float* __restrict__ sumlA, const float* __restrict__ sumexpA,
    const unsigned* __restrict__ cntA, const unsigned* __restrict__ wrongA,
    float* __restrict__ out, int N, int b)
{
    __shared__ unsigned swU[16];
    __shared__ float swF[16];
    __shared__ unsigned sTot;
    const int r = threadIdx.x;
    const int lane = r & 63, wv = r >> 6;

    int f = flags[r];
    bool row_m1 = (f == -1);
    float mdot = bestA[r];
    float m = mdot * INV_T;
    int qmax1 = flagsA[r];  // qf@argmax + 1 (0 => qf==-1)
    float s = sumexpA[r];
    float l = sumlA[r];
    unsigned cnt = cntA[r];

    float rowsum;
    if (row_m1) {
        rowsum = 0.f;  // row zeroed -> every exp==1 -> all excluded
    } else {
        float adj = s - ((qmax1 == 0) ? 0.f : exp2f(mdot * K2E));
        rowsum = exp2f(-mdot * K2E) * adj;
        rowsum = fmaxf(rowsum, 0.f);
    }
    float sum_lfp = INV_T * l - (float)cnt * m;
    bool ispos = (!row_m1) && (qmax1 - 1 == f);
    unsigned nnz = cnt - (ispos ? 1u : 0u);

    int nit = *n_iter_p;
    bool revise = false;
    if (nit >= 0) {
        float ub = (float)cnt / ((float)(N - (int)cnt) + 1e-6f);
        if (ub > 10.0f) {
            unsigned wr = wrongA[r];
            float wf = (float)wr;
            float pf = (float)(N - (int)wr);
            revise = (wf / (pf + 1e-6f)) > 10.0f;
        }
    }
    out[1 + r] = (float)(revise ? 0 : f);
    float eff_suml = revise ? 0.f : sum_lfp;
    unsigned eff_nnz = revise ? 0u : nnz;

    unsigned nn = eff_nnz;
#pragma unroll
    for (int off = 1; off < 64; off <<= 1) nn += __shfl_xor(nn, off);
    if (lane == 0) swU[wv] = nn;
    __syncthreads();
    if (r == 0) {
        unsigned tot = 0;
#pragma unroll
        for (int i = 0; i < 16; ++i) tot += swU[i];
        sTot = tot;
    }
    __syncthreads();
    unsigned total_nnz = sTot;

    float row_lp = eff_suml - (float)N * logf(rowsum + 1e-12f);
    float contrib = (total_nnz > 0u && rowsum > 0.f && row_lp < 0.f)
                        ? row_lp / (float)total_nnz
                        : 0.f;
#pragma unroll
    for (int off = 1; off < 64; off <<= 1) contrib += __shfl_xor(contrib, off);
    if (lane == 0) swF[wv] = contrib;
    __syncthreads();
    if (r == 0) {
        float tot = 0.f;
#pragma unroll
        for (int i = 0; i < 16; ++i) tot += swF[i];
        out[0] = -(tot / (float)b);  // TEMP/BASE_TEMP == 1
    }
}

extern "C" void kernel_launch(void* const* d_in, const int* in_sizes, int n_in,
                              void* d_out, int out_size, void* d_ws,
                              size_t ws_size, hipStream_t stream)
{
    const float* Q = (const float*)d_in[0];
    const float* Kall = (const float*)d_in[1];
    const int* flags = (const int*)d_in[2];
    const int* qfall = (const int*)d_in[3];
    const int* n_iter = (const int*)d_in[4];
    float* out = (float*)d_out;

    const int b = in_sizes[2];      // 1024
    const int total = in_sizes[3];  // 33792
    const int N = total - b;        // 32768
    const float* Kv = Kall + (size_t)b * 128;
    const int* qf = qfall + b;

    char* wsb = (char*)d_ws;
    float* bestA = (float*)wsb;
    int* flagsA = (int*)(wsb + 4096);
    float* sumlA = (float*)(wsb + 8192);
    float* sumexpA = (float*)(wsb + 12288);
    unsigned* cntA = (unsigned*)(wsb + 16384);
    unsigned* wrongA = (unsigned*)(wsb + 20480);
    unsigned* histP = (unsigned*)(wsb + 24576);
    float4* part = (float4*)(wsb + 32768);
    char* KbB = wsb + 32768 + (size_t)64 * b * 16;  // +1 MB
    unsigned short* Qb = (unsigned short*)(KbB + (size_t)N * 256);

    int nconv = (N + b) * 16;
    convert_kernel<<<(nconv + 255) / 256, 256, 0, stream>>>(
        Q, Kv, qf, Qb, KbB, histP, wrongA, N, b);

    dim3 grid(N / 512, b / 128);
    gemm_kernel<<<grid, 512, 0, stream>>>(Qb, KbB, flags, qf, part, b);
    reduce_kernel<<<b / 64, 256, 0, stream>>>(part, flags, histP, Q, Kv, qf,
                                              bestA, flagsA, sumlA, sumexpA,
                                              cntA, wrongA, N, b);
    final_kernel<<<1, b, 0, stream>>>(flags, n_iter, bestA, flagsA, sumlA,
                                      sumexpA, cntA, wrongA, out, N, b);
}

// Round 11
// 44.077 us; speedup vs baseline: 3.3239x; 1.8685x over previous
//
#include <hip/hip_runtime.h>
#include <stdint.h>

// ---------------------------------------------------------------------------
// LIL loss v11 == v8 exactly (proven 44.3us, absmax 0). 4 launches.
//  convert: f32->bf16 (K swizzled 64-col/16KB tiles, Q plain) + qf hist
//           partials + zero wrongA.
//  gemm:    grid (N/512, b/128); 512 thr (8 waves). A in regs; B 64-col
//           subtiles double-buffered (2x16KB) via global_load_lds from
//           pre-swizzled ws. ROLLED t-loop (unrolling it spills: v9/v10
//           showed 120MB scratch WRITE_SIZE, +40us). Per-element:
//           class-encoded max, sum exp2 via bias-fma, sum dot over
//           positives. One partial slice per block.
//  reduce:  fold 64 slices/row + hist; exact wrong_cnt fallback scan for
//           rows that could revise (uniform early-exit normally).
//  final:   per-row finalize + 2 shuffle-reductions -> loss + flags out.
// ws: [0K) bestA f32[b] | [4K) flagsA | [8K) sumlA | [12K) sumexpA
//     [16K) cntA | [20K) wrongA | [24K) histP u32[64][32]
//     [32K) part float4[64*b] (1 MB) | [+1M) KbB bf16 swizzled (8 MB)
//     [+9M) Qb bf16[b*128]
// ---------------------------------------------------------------------------

typedef short bf16x8 __attribute__((ext_vector_type(8)));
typedef unsigned short ushort8v __attribute__((ext_vector_type(8)));
typedef float f32x4 __attribute__((ext_vector_type(4)));

#define INV_T 14.285714285714286f  // 1/0.07
#define K2E 20.609929155698604f    // log2(e)/0.07

__device__ __forceinline__ unsigned short f2bf(float x) {
    unsigned u = __float_as_uint(x);
    return (unsigned short)((u + 0x7FFFu + ((u >> 16) & 1u)) >> 16);
}
__device__ __forceinline__ ushort8v cvt8(const float4* s4) {
    float4 a = s4[0], b = s4[1];
    ushort8v v;
    v[0] = f2bf(a.x); v[1] = f2bf(a.y); v[2] = f2bf(a.z); v[3] = f2bf(a.w);
    v[4] = f2bf(b.x); v[5] = f2bf(b.y); v[6] = f2bf(b.z); v[7] = f2bf(b.w);
    return v;
}
__device__ __forceinline__ void gload_lds16(const void* g, void* l) {
    __builtin_amdgcn_global_load_lds(
        (const __attribute__((address_space(1))) unsigned int*)g,
        (__attribute__((address_space(3))) unsigned int*)l, 16, 0, 0);
}

__global__ void convert_kernel(const float* __restrict__ Q,
                               const float* __restrict__ Kv,
                               const int* __restrict__ qf,
                               unsigned short* __restrict__ Qb,
                               char* __restrict__ KbB,
                               unsigned* __restrict__ histP,
                               unsigned* __restrict__ wrongA, int N, int b) {
    __shared__ unsigned lh[32];
    const int t = threadIdx.x;
    const int blk = blockIdx.x;
    if (blk < 64) {
        if (t < 32) lh[t] = 0u;
        __syncthreads();
        int j0 = blk * 512;
        atomicAdd(&lh[qf[j0 + t] + 1], 1u);
        atomicAdd(&lh[qf[j0 + 256 + t] + 1], 1u);
        __syncthreads();
        if (t < 32) histP[blk * 32 + t] = lh[t];
    }
    int i = blk * 256 + t;
    if (i < b) wrongA[i] = 0u;
    int nk = N * 16;
    if (i < nk) {
        int row = i >> 4, kc = i & 15;
        ushort8v v = cvt8(reinterpret_cast<const float4*>(
            Kv + (size_t)row * 128 + kc * 8));
        int tb = row >> 6, rr = row & 63;
        int off = tb * 16384 + ((rr * 256 + kc * 16) ^ ((rr & 7) << 4));
        *reinterpret_cast<ushort8v*>(KbB + off) = v;
    } else if (i < nk + b * 16) {
        int j = i - nk;
        int row = j >> 4, kc = j & 15;
        ushort8v v = cvt8(reinterpret_cast<const float4*>(
            Q + (size_t)row * 128 + kc * 8));
        *reinterpret_cast<ushort8v*>((char*)Qb + row * 256 + kc * 16) = v;
    }
}

__global__ __launch_bounds__(512, 2) void gemm_kernel(
    const unsigned short* __restrict__ Qb, const char* __restrict__ KbB,
    const int* __restrict__ flags, const int* __restrict__ qf,
    float4* __restrict__ part, int b)
{
    __shared__ __align__(16) char sB[2][16384];
    const int tid = threadIdx.x;
    const int lane = tid & 63, g = lane >> 4, q = lane & 15;
    const int wave = tid >> 6, wr = wave >> 1, wc = wave & 1;
    const int bx = blockIdx.x;
    const int r0 = blockIdx.y * 128;

    bf16x8 af[2][4];
#pragma unroll
    for (int mi = 0; mi < 2; ++mi) {
        int row = r0 + 32 * wr + 16 * mi + q;
#pragma unroll
        for (int ks = 0; ks < 4; ++ks)
            af[mi][ks] = *reinterpret_cast<const bf16x8*>(
                Qb + (size_t)row * 128 + ks * 32 + g * 8);
    }
    unsigned flpack[2];
#pragma unroll
    for (int mi = 0; mi < 2; ++mi) {
        unsigned p = 0;
#pragma unroll
        for (int reg = 0; reg < 4; ++reg) {
            int f = flags[r0 + 32 * wr + 16 * mi + 4 * g + reg];
            unsigned byte = (f < 0) ? 255u : (unsigned)(f + 1);
            p |= byte << (8 * reg);
        }
        flpack[mi] = p;
    }

    float bestp[8], se[8], sl[8];
#pragma unroll
    for (int r = 0; r < 8; ++r) { bestp[r] = -3.0e38f; se[r] = 0.f; sl[r] = 0.f; }

#define STAGE(buf, gt)                                                 \
    {                                                                  \
        const char* s_ = KbB + (size_t)(gt) * 16384 + tid * 16;        \
        char* d_ = &sB[buf][tid * 16];                                 \
        gload_lds16(s_, d_);                                           \
        gload_lds16(s_ + 8192, d_ + 8192);                             \
    }

    STAGE(0, bx * 8);

    for (int t = 0; t < 8; ++t) {
        __syncthreads();
        if (t < 7) STAGE((t + 1) & 1, bx * 8 + t + 1);
        const char* bb = sB[t & 1];

        f32x4 acc[2][2];
#pragma unroll
        for (int mi = 0; mi < 2; ++mi)
#pragma unroll
            for (int ni = 0; ni < 2; ++ni) acc[mi][ni] = (f32x4){0, 0, 0, 0};

#pragma unroll
        for (int ks = 0; ks < 4; ++ks) {
            bf16x8 bf[2];
#pragma unroll
            for (int ni = 0; ni < 2; ++ni) {
                int rr = 32 * wc + 16 * ni + q;
                bf[ni] = *reinterpret_cast<const bf16x8*>(
                    bb + ((rr * 256 + ks * 64 + g * 16) ^ ((rr & 7) << 4)));
            }
#pragma unroll
            for (int mi = 0; mi < 2; ++mi)
#pragma unroll
                for (int ni = 0; ni < 2; ++ni)
                    acc[mi][ni] = __builtin_amdgcn_mfma_f32_16x16x32_bf16(
                        af[mi][ks], bf[ni], acc[mi][ni], 0, 0, 0);
        }

        int cb = bx * 512 + t * 64 + 32 * wc + q;
        unsigned qv1[2] = {(unsigned)(qf[cb] + 1), (unsigned)(qf[cb + 16] + 1)};
        // bias -1024: exp2 underflows to exact 0 for qf==-1 columns;
        // fma(dot,K2E,+0) rounds identically to dot*K2E on the live path.
        float bias[2] = {(qv1[0] == 0u) ? -1024.f : 0.f,
                         (qv1[1] == 0u) ? -1024.f : 0.f};
#pragma unroll
        for (int mi = 0; mi < 2; ++mi)
#pragma unroll
            for (int reg = 0; reg < 4; ++reg) {
                int rr8 = mi * 4 + reg;
                unsigned fc = (flpack[mi] >> (8 * reg)) & 255u;
                float bp = bestp[rr8], s = se[rr8], l = sl[rr8];
#pragma unroll
                for (int ni = 0; ni < 2; ++ni) {
                    float dot = acc[mi][ni][reg];
                    s += exp2f(__builtin_fmaf(dot, K2E, bias[ni]));
                    l += (qv1[ni] == fc) ? dot : 0.f;
                    float dp = __uint_as_float(
                        (__float_as_uint(dot) & ~31u) | qv1[ni]);
                    bp = fmaxf(bp, dp);
                }
                bestp[rr8] = bp; se[rr8] = s; sl[rr8] = l;
            }
    }

    float4* scr = (float4*)sB;  // 256 float4, overlays sB[0]
#pragma unroll
    for (int rr8 = 0; rr8 < 8; ++rr8) {
        float bp = bestp[rr8], s = se[rr8], l = sl[rr8];
#pragma unroll
        for (int off = 1; off < 16; off <<= 1) {
            float ob = __shfl_xor(bp, off);
            float os = __shfl_xor(s, off);
            float ol = __shfl_xor(l, off);
            bp = fmaxf(bp, ob);
            s += os;
            l += ol;
        }
        if (q == 0) {
            int rl = 32 * wr + 16 * (rr8 >> 2) + 4 * g + (rr8 & 3);
            scr[wc * 128 + rl] = make_float4(bp, s, l, 0.f);
        }
    }
    __syncthreads();
    if (tid < 128) {
        float4 a = scr[tid], c = scr[128 + tid];
        part[(size_t)bx * b + r0 + tid] =
            make_float4(fmaxf(a.x, c.x), a.y + c.y, a.z + c.z, 0.f);
    }
}

// 16 blocks x 64 rows: fold slices + hist; then (rarely) exact wrong_cnt
// scan for any row whose revise upper-bound cnt/(N-cnt) could exceed 10.
__global__ __launch_bounds__(256) void reduce_kernel(
    const float4* __restrict__ part, const int* __restrict__ flags,
    const unsigned* __restrict__ histP, const float* __restrict__ Q,
    const float* __restrict__ Kv, const int* __restrict__ qf,
    float* __restrict__ bestA, int* __restrict__ flagsA,
    float* __restrict__ sumlA, float* __restrict__ sumexpA,
    unsigned* __restrict__ cntA, unsigned* __restrict__ wrongA, int N, int b)
{
    __shared__ float4 red[4][64];
    __shared__ unsigned sh[32];
    __shared__ float sB64[64], sL64[64];
    __shared__ unsigned sC64[64];
    __shared__ int sList[64];
    __shared__ int sNum;
    __shared__ unsigned sWp;
    __shared__ float sQrow[128];

    const int t = threadIdx.x;
    if (t == 0) sNum = 0;
    if (t < 32) {
        unsigned s = 0;
#pragma unroll
        for (int i = 0; i < 64; ++i) s += histP[i * 32 + t];
        sh[t] = s;
    }
    const int rl = t & 63;
    const int r = blockIdx.x * 64 + rl;
    const int pg = t >> 6;
    float bp = -3.0e38f, s = 0.f, l = 0.f;
    for (int cs = pg; cs < 64; cs += 4) {
        float4 p = part[(size_t)cs * b + r];
        bp = fmaxf(bp, p.x);
        s += p.y;
        l += p.z;
    }
    red[pg][rl] = make_float4(bp, s, l, 0.f);
    __syncthreads();
    if (t < 64) {
        const int rr = blockIdx.x * 64 + t;
        bp = -3.0e38f; s = 0.f; l = 0.f;
#pragma unroll
        for (int i = 0; i < 4; ++i) {
            float4 p = red[i][t];
            bp = fmaxf(bp, p.x);
            s += p.y;
            l += p.z;
        }
        bestA[rr] = bp;
        flagsA[rr] = (int)(__float_as_uint(bp) & 31u);  // qf@argmax + 1
        sumexpA[rr] = s;
        sumlA[rr] = l;
        int f = flags[rr];
        unsigned c = (f >= 0) ? sh[f + 1] : 0u;
        cntA[rr] = c;
        sB64[t] = bp; sL64[t] = l; sC64[t] = c;
        float ub = (float)c / ((float)(N - (int)c) + 1e-6f);
        if (ub > 10.0f) {
            int slot = atomicAdd(&sNum, 1);
            sList[slot] = t;
        }
    }
    __syncthreads();
    const int nt = sNum;  // uniform; normally 0
    for (int i = 0; i < nt; ++i) {
        int rloc = sList[i];
        int rr = blockIdx.x * 64 + rloc;
        if (t == 0) sWp = 0u;
        if (t < 128) sQrow[t] = Q[(size_t)rr * 128 + t];
        __syncthreads();
        float m = sB64[rloc] * INV_T;
        unsigned c = sC64[rloc];
        float mean = (INV_T * sL64[rloc] - (float)c * m) / (float)N;
        int f = flags[rr];
        int wp = 0;
        for (int j = t; j < N; j += 256) {
            float dot = 0.f;
            const float* kr = Kv + (size_t)j * 128;
            for (int k = 0; k < 128; ++k) dot += sQrow[k] * kr[k];
            bool mask = (f == qf[j]) && (f != -1);
            float lfp = mask ? (dot * INV_T - m) : 0.f;
            if (lfp < mean) wp++;
        }
        atomicAdd(&sWp, (unsigned)wp);
        __syncthreads();
        if (t == 0) wrongA[rr] = sWp;
        __syncthreads();
    }
}

__global__ __launch_bounds__(1024) void final_kernel(
    const int* __restrict__ flags, const int* __restrict__ n_iter_p,
    const float* __restrict__ bestA, const int* __restrict__ flagsA,
    const float* __restrict__ sumlA, const float* __restrict__ sumexpA,
    const unsigned* __restrict__ cntA, const unsigned* __restrict__ wrongA,
    float* __restrict__ out, int N, int b)
{
    __shared__ unsigned swU[16];
    __shared__ float swF[16];
    __shared__ unsigned sTot;
    const int r = threadIdx.x;
    const int lane = r & 63, wv = r >> 6;

    int f = flags[r];
    bool row_m1 = (f == -1);
    float mdot = bestA[r];
    float m = mdot * INV_T;
    int qmax1 = flagsA[r];  // qf@argmax + 1 (0 => qf==-1)
    float s = sumexpA[r];
    float l = sumlA[r];
    unsigned cnt = cntA[r];

    float rowsum;
    if (row_m1) {
        rowsum = 0.f;  // row zeroed -> every exp==1 -> all excluded
    } else {
        float adj = s - ((qmax1 == 0) ? 0.f : exp2f(mdot * K2E));
        rowsum = exp2f(-mdot * K2E) * adj;
        rowsum = fmaxf(rowsum, 0.f);
    }
    float sum_lfp = INV_T * l - (float)cnt * m;
    bool ispos = (!row_m1) && (qmax1 - 1 == f);
    unsigned nnz = cnt - (ispos ? 1u : 0u);

    int nit = *n_iter_p;
    bool revise = false;
    if (nit >= 0) {
        float ub = (float)cnt / ((float)(N - (int)cnt) + 1e-6f);
        if (ub > 10.0f) {
            unsigned wr = wrongA[r];
            float wf = (float)wr;
            float pf = (float)(N - (int)wr);
            revise = (wf / (pf + 1e-6f)) > 10.0f;
        }
    }
    out[1 + r] = (float)(revise ? 0 : f);
    float eff_suml = revise ? 0.f : sum_lfp;
    unsigned eff_nnz = revise ? 0u : nnz;

    unsigned nn = eff_nnz;
#pragma unroll
    for (int off = 1; off < 64; off <<= 1) nn += __shfl_xor(nn, off);
    if (lane == 0) swU[wv] = nn;
    __syncthreads();
    if (r == 0) {
        unsigned tot = 0;
#pragma unroll
        for (int i = 0; i < 16; ++i) tot += swU[i];
        sTot = tot;
    }
    __syncthreads();
    unsigned total_nnz = sTot;

    float row_lp = eff_suml - (float)N * logf(rowsum + 1e-12f);
    float contrib = (total_nnz > 0u && rowsum > 0.f && row_lp < 0.f)
                        ? row_lp / (float)total_nnz
                        : 0.f;
#pragma unroll
    for (int off = 1; off < 64; off <<= 1) contrib += __shfl_xor(contrib, off);
    if (lane == 0) swF[wv] = contrib;
    __syncthreads();
    if (r == 0) {
        float tot = 0.f;
#pragma unroll
        for (int i = 0; i < 16; ++i) tot += swF[i];
        out[0] = -(tot / (float)b);  // TEMP/BASE_TEMP == 1
    }
}

extern "C" void kernel_launch(void* const* d_in, const int* in_sizes, int n_in,
                              void* d_out, int out_size, void* d_ws,
                              size_t ws_size, hipStream_t stream)
{
    const float* Q = (const float*)d_in[0];
    const float* Kall = (const float*)d_in[1];
    const int* flags = (const int*)d_in[2];
    const int* qfall = (const int*)d_in[3];
    const int* n_iter = (const int*)d_in[4];
    float* out = (float*)d_out;

    const int b = in_sizes[2];      // 1024
    const int total = in_sizes[3];  // 33792
    const int N = total - b;        // 32768
    const float* Kv = Kall + (size_t)b * 128;
    const int* qf = qfall + b;

    char* wsb = (char*)d_ws;
    float* bestA = (float*)wsb;
    int* flagsA = (int*)(wsb + 4096);
    float* sumlA = (float*)(wsb + 8192);
    float* sumexpA = (float*)(wsb + 12288);
    unsigned* cntA = (unsigned*)(wsb + 16384);
    unsigned* wrongA = (unsigned*)(wsb + 20480);
    unsigned* histP = (unsigned*)(wsb + 24576);
    float4* part = (float4*)(wsb + 32768);
    char* KbB = wsb + 32768 + (size_t)64 * b * 16;  // +1 MB
    unsigned short* Qb = (unsigned short*)(KbB + (size_t)N * 256);

    int nconv = (N + b) * 16;
    convert_kernel<<<(nconv + 255) / 256, 256, 0, stream>>>(
        Q, Kv, qf, Qb, KbB, histP, wrongA, N, b);

    dim3 grid(N / 512, b / 128);
    gemm_kernel<<<grid, 512, 0, stream>>>(Qb, KbB, flags, qf, part, b);
    reduce_kernel<<<b / 64, 256, 0, stream>>>(part, flags, histP, Q, Kv, qf,
                                              bestA, flagsA, sumlA, sumexpA,
                                              cntA, wrongA, N, b);
    final_kernel<<<1, b, 0, stream>>>(flags, n_iter, bestA, flagsA, sumlA,
                                      sumexpA, cntA, wrongA, out, N, b);
}